// Round 7
// baseline (1592.412 us; speedup 1.0000x reference)
//
#include <hip/hip_runtime.h>
#include <math.h>

#define BS   2048
#define SEQ  50
#define NPOS (BS * SEQ)

__device__ __forceinline__ float sigf(float x) { return 1.0f / (1.0f + __expf(-x)); }
__device__ __forceinline__ float tanhfast(float x) {
    float e = __expf(2.0f * x);
    return 1.0f - 2.0f / (e + 1.0f);
}

#define FMA4(A, X, W) \
    A = fmaf((X).x, (W).x, A); A = fmaf((X).y, (W).y, A); \
    A = fmaf((X).z, (W).z, A); A = fmaf((X).w, (W).w, A);

// ---------------------------------------------------------------------------
// prep_w: transpose weights into wave-contiguous streaming layouts (in ws).
//   wiT[(g*4+kk)*512 + t] = W_ih[(4*(t>>2)+g)*64  + (t&3)*16 + kk*4 ..+3]
//   whT[(g*8+kk)*512 + t] = W_hh[(4*(t>>2)+g)*128 + (t&3)*32 + kk*4 ..+3]
//   wqT[kk*64 + o]        = Wq[o*64 + kk*4 ..+3]   (wvT likewise)
// ---------------------------------------------------------------------------
__global__ __launch_bounds__(512) void prep_w(
    const float* __restrict__ Wih, const float* __restrict__ Whh,
    const float* __restrict__ Wq,  const float* __restrict__ Wv,
    float4* __restrict__ wiT, float4* __restrict__ whT,
    float4* __restrict__ wqT, float4* __restrict__ wvT)
{
    const int t = threadIdx.x;
    const int gq = t >> 2, kq = t & 3;
    #pragma unroll
    for (int g = 0; g < 4; ++g)
        #pragma unroll
        for (int kk = 0; kk < 4; ++kk)
            wiT[(g*4+kk)*512 + t] = *(const float4*)&Wih[(4*gq+g)*64 + kq*16 + kk*4];
    #pragma unroll
    for (int g = 0; g < 4; ++g)
        #pragma unroll
        for (int kk = 0; kk < 8; ++kk)
            whT[(g*8+kk)*512 + t] = *(const float4*)&Whh[(4*gq+g)*128 + kq*32 + kk*4];
    if (t < 64) {
        #pragma unroll
        for (int kk = 0; kk < 16; ++kk) {
            wqT[kk*64 + t] = *(const float4*)&Wq[t*64 + kk*4];
            wvT[kk*64 + t] = *(const float4*)&Wv[t*64 + kk*4];
        }
    }
}

// ---------------------------------------------------------------------------
// Kernel A: edge fusion + masked attention -> ctx. 64-thr blocks.
// wq/wv NOT register-resident (that demanded ~190 regs -> spill); streamed
// from transposed wqT/wvT (32 KB, L1-resident, contiguous per wave-load).
// Peak register demand ~60 -> safe under any compiler budget.
// ---------------------------------------------------------------------------
__global__ __launch_bounds__(64) void edge_attn_ctx(
    const float* __restrict__ seqs,   // [BS,SEQ,3,3,6]
    const float* __restrict__ ets,    // [BS,SEQ,3,3,4]
    const int*   __restrict__ masks,  // [BS,SEQ,3,3]
    const float* __restrict__ Wf, const float* __restrict__ bf,
    const float* __restrict__ Wk, const float* __restrict__ bk,
    const float* __restrict__ bq, const float* __restrict__ bv,
    const float4* __restrict__ wqT,   // [kk*64 + o]
    const float4* __restrict__ wvT,   // [kk*64 + o]
    float* __restrict__ ctx)          // [BS,SEQ,64]
{
    const int o = threadIdx.x;

    __shared__ float s_seq[54];
    __shared__ float s_et[36];
    __shared__ int   s_mask[9];
    __shared__ float s_edge[9 * 64];

    for (int p = blockIdx.x; p < NPOS; p += gridDim.x) {
        if (o < 54) s_seq[o]  = seqs[p * 54 + o];
        if (o < 36) s_et[o]   = ets[p * 36 + o];
        if (o < 9)  s_mask[o] = masks[p * 9 + o];
        __syncthreads();

        // reload small weights per position (L1-hot) -> short live ranges
        const float* wfp = &Wf[o * 19];
        float wf0=wfp[0], wf1=wfp[1], wf2=wfp[2], wf3=wfp[3], wf4=wfp[4],
              wf5=wfp[5], wf6=wfp[6], wf7=wfp[7], wf8=wfp[8], wf9=wfp[9];
        const float bfr = bf[o];

        #pragma unroll
        for (int e = 0; e < 9; ++e) {
            float v = bfr + wfp[10 + e];     // eye(9) concat term
            v = fmaf(s_seq[e*6+0], wf0, v);
            v = fmaf(s_seq[e*6+1], wf1, v);
            v = fmaf(s_seq[e*6+2], wf2, v);
            v = fmaf(s_seq[e*6+3], wf3, v);
            v = fmaf(s_seq[e*6+4], wf4, v);
            v = fmaf(s_seq[e*6+5], wf5, v);
            v = fmaf(s_et[e*4+0],  wf6, v);
            v = fmaf(s_et[e*4+1],  wf7, v);
            v = fmaf(s_et[e*4+2],  wf8, v);
            v = fmaf(s_et[e*4+3],  wf9, v);
            s_edge[e * 64 + o] = v;
        }
        const float* wkp = &Wk[o * 6];
        float key = bk[o];
        key = fmaf(s_seq[24], wkp[0], key);
        key = fmaf(s_seq[25], wkp[1], key);
        key = fmaf(s_seq[26], wkp[2], key);
        key = fmaf(s_seq[27], wkp[3], key);
        key = fmaf(s_seq[28], wkp[4], key);
        key = fmaf(s_seq[29], wkp[5], key);
        __syncthreads();

        const float bqr = bq[o], bvr = bv[o];
        float vv[9], att[9];
        #pragma unroll
        for (int e = 0; e < 9; ++e) {
            const float4* ep = (const float4*)&s_edge[e * 64];
            float q = 0.f, v = 0.f;
            #pragma unroll
            for (int kk = 0; kk < 16; ++kk) {
                float4 x = ep[kk];              // LDS broadcast (free)
                float4 a = wqT[kk*64 + o];      // contiguous 1KB wave-load, L1
                float4 b = wvT[kk*64 + o];
                FMA4(q, x, a)
                FMA4(v, x, b)
            }
            float qq = bqr + q;
            vv[e] = bvr + v;
            float a_ = key * qq;
            a_ += __shfl_xor(a_, 8, 16);
            a_ += __shfl_xor(a_, 4, 16);
            a_ += __shfl_xor(a_, 2, 16);
            a_ += __shfl_xor(a_, 1, 16);
            att[e] = a_ * 0.25f;   // / sqrt(16)
        }

        float mx = -3.0e38f;
        #pragma unroll
        for (int e = 0; e < 9; ++e) {
            att[e] = (s_mask[e] == 0) ? -1.0e10f : att[e];
            mx = fmaxf(mx, att[e]);
        }
        float ssum = 0.f;
        #pragma unroll
        for (int e = 0; e < 9; ++e) { att[e] = __expf(att[e] - mx); ssum += att[e]; }
        float inv = 1.f / ssum;
        float acc = 0.f;
        #pragma unroll
        for (int e = 0; e < 9; ++e) acc = fmaf(att[e], vv[e], acc);
        ctx[p * 64 + o] = acc * inv;
        __syncthreads();
    }
}

// ---------------------------------------------------------------------------
// Kernel C v5: G=4 gates x S=4 k-quarters, 8 rows, 256 blocks x 512 thr.
// Both weight matrices streamed (transposed, coalesced, L2-shared). LDS
// skewed so the 4 k-quarter readers hit disjoint bank spans:
//   s_x quarters at +20 floats (banks 0/20/8/28), s_h at +36 (banks 0/4/8/12).
// R6's 1.15e8 bank-conflict cycles came from k-halves 128/256 B apart.
// Registers: 32 acc + ~40 misc ~= 75 — no spill at any budget.
// ---------------------------------------------------------------------------
#define SGS 516   // s_g row stride (floats); 516*4B % 16 == 0, bank offset +4/row

#define RED2(A) A += __shfl_xor(A, 1); A += __shfl_xor(A, 2);
#define SEL(a,b,c,d) (kq == 0 ? (a) : kq == 1 ? (b) : kq == 2 ? (c) : (d))

#define XR(kk, r) { float4 x_ = sx4[(r)*20 + kq5 + (kk)]; \
    FMA4(A0##r, x_, w0_) FMA4(A1##r, x_, w1_) FMA4(A2##r, x_, w2_) FMA4(A3##r, x_, w3_) }

#define XK(kk) { \
    float4 w0_ = wiT[(0*4+(kk))*512 + t]; \
    float4 w1_ = wiT[(1*4+(kk))*512 + t]; \
    float4 w2_ = wiT[(2*4+(kk))*512 + t]; \
    float4 w3_ = wiT[(3*4+(kk))*512 + t]; \
    XR(kk,0) XR(kk,1) XR(kk,2) XR(kk,3) XR(kk,4) XR(kk,5) XR(kk,6) XR(kk,7) }

#define HR(kk, r) { float4 h_ = sh4[(r)*36 + kq9 + (kk)]; \
    FMA4(A0##r, h_, w0_) FMA4(A1##r, h_, w1_) FMA4(A2##r, h_, w2_) FMA4(A3##r, h_, w3_) }

#define HK(kk) { \
    float4 w0_ = whT[(0*8+(kk))*512 + t]; \
    float4 w1_ = whT[(1*8+(kk))*512 + t]; \
    float4 w2_ = whT[(2*8+(kk))*512 + t]; \
    float4 w3_ = whT[(3*8+(kk))*512 + t]; \
    HR(kk,0) HR(kk,1) HR(kk,2) HR(kk,3) HR(kk,4) HR(kk,5) HR(kk,6) HR(kk,7) }

__global__ __launch_bounds__(512) void lstm_out(
    const float*  __restrict__ ctx,   // [BS,SEQ,64]
    const float4* __restrict__ wiT,   // [(g*4+kk)*512 + t]
    const float4* __restrict__ whT,   // [(g*8+kk)*512 + t]
    const float*  __restrict__ b_ih, const float* __restrict__ b_hh,
    const float*  __restrict__ W_out, const float* __restrict__ b_out,
    float* __restrict__ out)          // [BS,64]
{
    const int t    = threadIdx.x;
    const int kq   = t & 3;
    const int kq5  = kq * 5;          // x quarter offset in float4s
    const int kq9  = kq * 9;          // h quarter offset in float4s
    const int row0 = blockIdx.x * 8;
    const int r2   = t >> 6;          // pointwise/staging row 0..7
    const int m    = t & 63;          // pointwise elem (m and m+64)

    const float bi0 = b_ih[m]       + b_hh[m];
    const float bf0 = b_ih[128 + m] + b_hh[128 + m];
    const float bg0 = b_ih[256 + m] + b_hh[256 + m];
    const float bo0 = b_ih[384 + m] + b_hh[384 + m];
    const float bi1 = b_ih[64 + m]  + b_hh[64 + m];
    const float bf1 = b_ih[192 + m] + b_hh[192 + m];
    const float bg1 = b_ih[320 + m] + b_hh[320 + m];
    const float bo1 = b_ih[448 + m] + b_hh[448 + m];

    __shared__ float s_x[8 * 80];     // quarters of 16 at cols 0/20/40/60
    __shared__ float s_h[8 * 144];    // quarters of 32 at cols 0/36/72/108
    __shared__ float s_g[8 * SGS];

    const float4* sx4 = (const float4*)s_x;
    const float4* sh4 = (const float4*)s_h;

    const int xcol  = (m >> 4) * 20 + (m & 15);
    const int hcol0 = (m >> 5) * 36 + (m & 31);
    const int hcol1 = (2 + (m >> 5)) * 36 + (m & 31);

    float c0 = 0.f, c1 = 0.f;

    for (int s = 0; s < SEQ; ++s) {
        s_x[r2 * 80 + xcol] = ctx[((row0 + r2) * SEQ + s) * 64 + m];
        __syncthreads();

        float A00=0.f,A01=0.f,A02=0.f,A03=0.f,A04=0.f,A05=0.f,A06=0.f,A07=0.f;
        float A10=0.f,A11=0.f,A12=0.f,A13=0.f,A14=0.f,A15=0.f,A16=0.f,A17=0.f;
        float A20=0.f,A21=0.f,A22=0.f,A23=0.f,A24=0.f,A25=0.f,A26=0.f,A27=0.f;
        float A30=0.f,A31=0.f,A32=0.f,A33=0.f,A34=0.f,A35=0.f,A36=0.f,A37=0.f;

        XK(0) XK(1) XK(2) XK(3)
        if (s > 0) {
            HK(0) HK(1) HK(2) HK(3) HK(4) HK(5) HK(6) HK(7)
        }

        RED2(A00) RED2(A01) RED2(A02) RED2(A03) RED2(A04) RED2(A05) RED2(A06) RED2(A07)
        RED2(A10) RED2(A11) RED2(A12) RED2(A13) RED2(A14) RED2(A15) RED2(A16) RED2(A17)
        RED2(A20) RED2(A21) RED2(A22) RED2(A23) RED2(A24) RED2(A25) RED2(A26) RED2(A27)
        RED2(A30) RED2(A31) RED2(A32) RED2(A33) RED2(A34) RED2(A35) RED2(A36) RED2(A37)

        {   // lane kq writes rows kq and kq+4, gates 4gq..4gq+3 (one b128 each)
            float4 glo = make_float4(SEL(A00,A01,A02,A03), SEL(A10,A11,A12,A13),
                                     SEL(A20,A21,A22,A23), SEL(A30,A31,A32,A33));
            float4 ghi = make_float4(SEL(A04,A05,A06,A07), SEL(A14,A15,A16,A17),
                                     SEL(A24,A25,A26,A27), SEL(A34,A35,A36,A37));
            const int gq4 = (t >> 2) << 2;
            *(float4*)&s_g[kq * SGS + gq4]       = glo;
            *(float4*)&s_g[(kq + 4) * SGS + gq4] = ghi;
        }
        __syncthreads();

        {   // pointwise for (r2, m) and (r2, m+64)
            const float* g0 = &s_g[r2 * SGS];
            float ig = sigf(g0[m] + bi0);
            float fg = sigf(g0[128 + m] + bf0);
            float gt = tanhfast(g0[256 + m] + bg0);
            float og = sigf(g0[384 + m] + bo0);
            c0 = fmaf(fg, c0, ig * gt);
            s_h[r2 * 144 + hcol0] = og * tanhfast(c0);

            float ih = sigf(g0[64 + m] + bi1);
            float fh = sigf(g0[192 + m] + bf1);
            float gh = tanhfast(g0[320 + m] + bg1);
            float oh = sigf(g0[448 + m] + bo1);
            c1 = fmaf(fh, c1, ih * gh);
            s_h[r2 * 144 + hcol1] = oh * tanhfast(c1);
        }
        __syncthreads();
    }

    // epilogue: out[row0+r2][m] = b_out[m] + h[r2] . W_out[m]
    {
        float acc = b_out[m];
        const float4* wp = (const float4*)&W_out[m * 128];
        #pragma unroll
        for (int q = 0; q < 4; ++q)
            #pragma unroll
            for (int i = 0; i < 8; ++i) {
                float4 h4 = sh4[r2 * 36 + q * 9 + i];   // broadcast read
                float4 w4 = wp[q * 8 + i];
                FMA4(acc, h4, w4)
            }
        out[(row0 + r2) * 64 + m] = acc;
    }
}

// ---------------------------------------------------------------------------
extern "C" void kernel_launch(void* const* d_in, const int* in_sizes, int n_in,
                              void* d_out, int out_size, void* d_ws, size_t ws_size,
                              hipStream_t stream) {
    (void)in_sizes; (void)n_in; (void)out_size; (void)ws_size;
    const float* seqs  = (const float*)d_in[0];
    const float* ets   = (const float*)d_in[1];
    const int*   masks = (const int*)d_in[2];
    const float* Wf  = (const float*)d_in[3];
    const float* bf  = (const float*)d_in[4];
    const float* Wk  = (const float*)d_in[5];
    const float* bk  = (const float*)d_in[6];
    const float* Wq  = (const float*)d_in[7];
    const float* bq  = (const float*)d_in[8];
    const float* Wv  = (const float*)d_in[9];
    const float* bv  = (const float*)d_in[10];
    const float* Wih = (const float*)d_in[11];
    const float* Whh = (const float*)d_in[12];
    const float* bih = (const float*)d_in[13];
    const float* bhh = (const float*)d_in[14];
    const float* Wo  = (const float*)d_in[15];
    const float* bo  = (const float*)d_in[16];

    // ws layout (16B-aligned): wiT 128K | whT 256K | wqT 16K | wvT 16K | ctx 26.2M
    char* ws = (char*)d_ws;
    float4* wiT = (float4*)(ws);
    float4* whT = (float4*)(ws + 131072);
    float4* wqT = (float4*)(ws + 131072 + 262144);
    float4* wvT = (float4*)(ws + 131072 + 262144 + 16384);
    float*  ctx = (float*) (ws + 131072 + 262144 + 16384 + 16384);

    hipLaunchKernelGGL(prep_w, dim3(1), dim3(512), 0, stream,
                       Wih, Whh, Wq, Wv, wiT, whT, wqT, wvT);
    hipLaunchKernelGGL(edge_attn_ctx, dim3(4096), dim3(64), 0, stream,
                       seqs, ets, masks, Wf, bf, Wk, bk, bq, bv, wqT, wvT, ctx);
    hipLaunchKernelGGL(lstm_out, dim3(256), dim3(512), 0, stream,
                       ctx, wiT, whT, bih, bhh, Wo, bo, (float*)d_out);
}

// Round 8
// 990.109 us; speedup vs baseline: 1.6083x; 1.6083x over previous
//
#include <hip/hip_runtime.h>
#include <math.h>

#define BS   2048
#define SEQ  50
#define NPOS (BS * SEQ)

__device__ __forceinline__ float sigf(float x) { return 1.0f / (1.0f + __expf(-x)); }
__device__ __forceinline__ float tanhfast(float x) {
    float e = __expf(2.0f * x);
    return 1.0f - 2.0f / (e + 1.0f);
}

// ---- macro toolkit: named-SSA values only (NO private arrays) -------------
#define FMA4(A, X, W) \
    A = fmaf((X).x, (W).x, A); A = fmaf((X).y, (W).y, A); \
    A = fmaf((X).z, (W).z, A); A = fmaf((X).w, (W).w, A);

#define LD16(P, N) \
    float4 N##0=(P)[0],  N##1=(P)[1],  N##2=(P)[2],  N##3=(P)[3], \
           N##4=(P)[4],  N##5=(P)[5],  N##6=(P)[6],  N##7=(P)[7], \
           N##8=(P)[8],  N##9=(P)[9],  N##10=(P)[10],N##11=(P)[11], \
           N##12=(P)[12],N##13=(P)[13],N##14=(P)[14],N##15=(P)[15];

#define LD8(P, N) \
    float4 N##0=(P)[0], N##1=(P)[1], N##2=(P)[2], N##3=(P)[3], \
           N##4=(P)[4], N##5=(P)[5], N##6=(P)[6], N##7=(P)[7];

// ---------------------------------------------------------------------------
// Kernel A: unchanged from R6 (proven ~320 us; not the target this round).
// ---------------------------------------------------------------------------
__global__
__attribute__((amdgpu_flat_work_group_size(64, 64), amdgpu_waves_per_eu(2, 2)))
void edge_attn_ctx(
    const float* __restrict__ seqs,   // [BS,SEQ,3,3,6]
    const float* __restrict__ ets,    // [BS,SEQ,3,3,4]
    const int*   __restrict__ masks,  // [BS,SEQ,3,3]
    const float* __restrict__ Wf, const float* __restrict__ bf,
    const float* __restrict__ Wk, const float* __restrict__ bk,
    const float* __restrict__ Wq, const float* __restrict__ bq,
    const float* __restrict__ Wv, const float* __restrict__ bv,
    float* __restrict__ ctx)          // [BS,SEQ,64]
{
    const int o = threadIdx.x;

    const float4* qp = (const float4*)&Wq[o * 64];
    LD16(qp, wq)
    const float4* vp = (const float4*)&Wv[o * 64];
    LD16(vp, wv)

    const float* wfp = &Wf[o * 19];
    float wf0=wfp[0], wf1=wfp[1], wf2=wfp[2], wf3=wfp[3], wf4=wfp[4], wf5=wfp[5],
          wf6=wfp[6], wf7=wfp[7], wf8=wfp[8], wf9=wfp[9];
    float wfe0=wfp[10], wfe1=wfp[11], wfe2=wfp[12], wfe3=wfp[13], wfe4=wfp[14],
          wfe5=wfp[15], wfe6=wfp[16], wfe7=wfp[17], wfe8=wfp[18];
    const float* wkp = &Wk[o * 6];
    float wk0=wkp[0], wk1=wkp[1], wk2=wkp[2], wk3=wkp[3], wk4=wkp[4], wk5=wkp[5];

    const float bfr = bf[o], bkr = bk[o], bqr = bq[o], bvr = bv[o];

    __shared__ float s_seq[54];
    __shared__ float s_et[36];
    __shared__ int   s_mask[9];
    __shared__ float s_edge[9 * 64];

    for (int p = blockIdx.x; p < NPOS; p += gridDim.x) {
        if (o < 54) s_seq[o]  = seqs[p * 54 + o];
        if (o < 36) s_et[o]   = ets[p * 36 + o];
        if (o < 9)  s_mask[o] = masks[p * 9 + o];
        __syncthreads();

        float wfe[9] = {wfe0,wfe1,wfe2,wfe3,wfe4,wfe5,wfe6,wfe7,wfe8};
        #pragma unroll
        for (int e = 0; e < 9; ++e) {
            float v = bfr + wfe[e];
            v = fmaf(s_seq[e*6+0], wf0, v);
            v = fmaf(s_seq[e*6+1], wf1, v);
            v = fmaf(s_seq[e*6+2], wf2, v);
            v = fmaf(s_seq[e*6+3], wf3, v);
            v = fmaf(s_seq[e*6+4], wf4, v);
            v = fmaf(s_seq[e*6+5], wf5, v);
            v = fmaf(s_et[e*4+0],  wf6, v);
            v = fmaf(s_et[e*4+1],  wf7, v);
            v = fmaf(s_et[e*4+2],  wf8, v);
            v = fmaf(s_et[e*4+3],  wf9, v);
            s_edge[e * 64 + o] = v;
        }
        float key = bkr;
        key = fmaf(s_seq[24], wk0, key);
        key = fmaf(s_seq[25], wk1, key);
        key = fmaf(s_seq[26], wk2, key);
        key = fmaf(s_seq[27], wk3, key);
        key = fmaf(s_seq[28], wk4, key);
        key = fmaf(s_seq[29], wk5, key);
        __syncthreads();

        float vv[9], att[9];
        #pragma unroll
        for (int e = 0; e < 9; ++e) {
            const float4* ep = (const float4*)&s_edge[e * 64];
            float q = 0.f, v = 0.f;
            {
                float4 t;
                t=ep[0];  FMA4(q,t,wq0)  FMA4(v,t,wv0)
                t=ep[1];  FMA4(q,t,wq1)  FMA4(v,t,wv1)
                t=ep[2];  FMA4(q,t,wq2)  FMA4(v,t,wv2)
                t=ep[3];  FMA4(q,t,wq3)  FMA4(v,t,wv3)
                t=ep[4];  FMA4(q,t,wq4)  FMA4(v,t,wv4)
                t=ep[5];  FMA4(q,t,wq5)  FMA4(v,t,wv5)
                t=ep[6];  FMA4(q,t,wq6)  FMA4(v,t,wv6)
                t=ep[7];  FMA4(q,t,wq7)  FMA4(v,t,wv7)
                t=ep[8];  FMA4(q,t,wq8)  FMA4(v,t,wv8)
                t=ep[9];  FMA4(q,t,wq9)  FMA4(v,t,wv9)
                t=ep[10]; FMA4(q,t,wq10) FMA4(v,t,wv10)
                t=ep[11]; FMA4(q,t,wq11) FMA4(v,t,wv11)
                t=ep[12]; FMA4(q,t,wq12) FMA4(v,t,wv12)
                t=ep[13]; FMA4(q,t,wq13) FMA4(v,t,wv13)
                t=ep[14]; FMA4(q,t,wq14) FMA4(v,t,wv14)
                t=ep[15]; FMA4(q,t,wq15) FMA4(v,t,wv15)
            }
            float qq = bqr + q;
            vv[e] = bvr + v;
            float a_ = key * qq;
            a_ += __shfl_xor(a_, 8, 16);
            a_ += __shfl_xor(a_, 4, 16);
            a_ += __shfl_xor(a_, 2, 16);
            a_ += __shfl_xor(a_, 1, 16);
            att[e] = a_ * 0.25f;   // / sqrt(16)
        }

        float mx = -3.0e38f;
        #pragma unroll
        for (int e = 0; e < 9; ++e) {
            att[e] = (s_mask[e] == 0) ? -1.0e10f : att[e];
            mx = fmaxf(mx, att[e]);
        }
        float ssum = 0.f;
        #pragma unroll
        for (int e = 0; e < 9; ++e) { att[e] = __expf(att[e] - mx); ssum += att[e]; }
        float inv = 1.f / ssum;
        float acc = 0.f;
        #pragma unroll
        for (int e = 0; e < 9; ++e) acc = fmaf(att[e], vv[e], acc);
        ctx[p * 64 + o] = acc * inv;
        __syncthreads();
    }
}

// ---------------------------------------------------------------------------
// Kernel C v6 = R6 (best: 720 us, FETCH 19 MB, no spill) + LDS bank-skew.
// R6's 1.15e8 conflict cycles: the wave's two concurrent k-half addresses
// were 128 B / 256 B apart = same bank quad (delta % 32 dwords == 0).
// Fix: x rows 68 floats (half1 at col 36, delta=36 dwords=+4 banks);
//      h rows 132 floats (half1 at col 68, delta=68 dwords=+4 banks).
// Weight streams stay DIRECT from d_in (scattered but L2-resident; do NOT
// transpose into ws — R7 showed LICM hoists clean loads -> scratch spill).
// ---------------------------------------------------------------------------
#define XROW 68
#define HROW 132

#define SX4(r) ((const float4*)&s_x[(r) * XROW + koff])
#define SH4(r) ((const float4*)&s_h[(r) * HROW + koff2])

#define XDOT(kk) { float4 x4_; \
    x4_ = SX4(0)[kk]; FMA4(aA0,x4_,wiA##kk) FMA4(aB0,x4_,wiB##kk) \
    x4_ = SX4(1)[kk]; FMA4(aA1,x4_,wiA##kk) FMA4(aB1,x4_,wiB##kk) \
    x4_ = SX4(2)[kk]; FMA4(aA2,x4_,wiA##kk) FMA4(aB2,x4_,wiB##kk) \
    x4_ = SX4(3)[kk]; FMA4(aA3,x4_,wiA##kk) FMA4(aB3,x4_,wiB##kk) \
    x4_ = SX4(4)[kk]; FMA4(aA4,x4_,wiA##kk) FMA4(aB4,x4_,wiB##kk) \
    x4_ = SX4(5)[kk]; FMA4(aA5,x4_,wiA##kk) FMA4(aB5,x4_,wiB##kk) \
    x4_ = SX4(6)[kk]; FMA4(aA6,x4_,wiA##kk) FMA4(aB6,x4_,wiB##kk) \
    x4_ = SX4(7)[kk]; FMA4(aA7,x4_,wiA##kk) FMA4(aB7,x4_,wiB##kk) }

#define HROW2(r, g) { float4 h0_, h1_; \
    h0_ = SH4(r)[2*(g)]; h1_ = SH4(r)[2*(g)+1]; \
    FMA4(aA##r,h0_,wa0_) FMA4(aA##r,h1_,wa1_) \
    FMA4(aB##r,h0_,wb0_) FMA4(aB##r,h1_,wb1_) }

#define HGRP(g) { \
    float4 wa0_=whAp[2*(g)], wa1_=whAp[2*(g)+1]; \
    float4 wb0_=whBp[2*(g)], wb1_=whBp[2*(g)+1]; \
    HROW2(0,g) HROW2(1,g) HROW2(2,g) HROW2(3,g) \
    HROW2(4,g) HROW2(5,g) HROW2(6,g) HROW2(7,g) }

#define REDW(r) { aA##r += __shfl_xor(aA##r, 1); aB##r += __shfl_xor(aB##r, 1); \
    s_g[(r) * 512 + t] = kh ? aB##r : aA##r; }

__global__ __launch_bounds__(512)
void lstm_out(
    const float* __restrict__ ctx,    // [BS,SEQ,64]
    const float* __restrict__ W_ih,   // [512,64]
    const float* __restrict__ W_hh,   // [512,128]
    const float* __restrict__ b_ih, const float* __restrict__ b_hh,
    const float* __restrict__ W_out,  // [64,128]
    const float* __restrict__ b_out,  // [64]
    float* __restrict__ out)          // [BS,64]
{
    const int t    = threadIdx.x;
    const int gg   = t >> 1;          // gate pair 0..255
    const int kh   = t & 1;           // k-half
    const int jA   = gg * 2, jB = jA + 1;
    const int row0 = blockIdx.x * 8;
    const int r2   = t >> 6;          // pointwise row 0..7
    const int m    = t & 63;          // pointwise elem (m and m+64)
    const int koff = kh * 36;         // x k-half offset (floats): +4 banks
    const int koff2= kh * 68;         // h k-half offset (floats): +4 banks

    // resident W_ih half-rows for both gates: 16 float4 = 64 VGPR
    const float4* wiAp = (const float4*)&W_ih[jA * 64 + kh * 32];
    LD8(wiAp, wiA)
    const float4* wiBp = (const float4*)&W_ih[jB * 64 + kh * 32];
    LD8(wiBp, wiB)

    // W_hh stream bases (direct from d_in: scattered but L2-resident)
    const float4* whAp = (const float4*)&W_hh[jA * 128 + kh * 64];
    const float4* whBp = (const float4*)&W_hh[jB * 128 + kh * 64];

    // pointwise biases (gate order i,f,g,o = rows 0/128/256/384)
    const float bi0 = b_ih[m]       + b_hh[m];
    const float bf0 = b_ih[128 + m] + b_hh[128 + m];
    const float bg0 = b_ih[256 + m] + b_hh[256 + m];
    const float bo0 = b_ih[384 + m] + b_hh[384 + m];
    const float bi1 = b_ih[64 + m]  + b_hh[64 + m];
    const float bf1 = b_ih[192 + m] + b_hh[192 + m];
    const float bg1 = b_ih[320 + m] + b_hh[320 + m];
    const float bo1 = b_ih[448 + m] + b_hh[448 + m];

    __shared__ float s_x[8 * XROW];   // k-halves at cols 0 / 36
    __shared__ float s_h[8 * HROW];   // k-halves at cols 0 / 68
    __shared__ float s_g[8 * 512];

    const int xcol  = m + ((m >> 5) << 2);        // m<32: m ; m>=32: m+4
    const int hcol0 = m;                          // h[0..63]   -> cols 0..63
    const int hcol1 = 68 + m;                     // h[64..127] -> cols 68..131

    float c0 = 0.f, c1 = 0.f;

    for (int s = 0; s < SEQ; ++s) {
        s_x[r2 * XROW + xcol] = ctx[((row0 + r2) * SEQ + s) * 64 + m];
        __syncthreads();

        float aA0=0.f,aA1=0.f,aA2=0.f,aA3=0.f,aA4=0.f,aA5=0.f,aA6=0.f,aA7=0.f;
        float aB0=0.f,aB1=0.f,aB2=0.f,aB3=0.f,aB4=0.f,aB5=0.f,aB6=0.f,aB7=0.f;

        XDOT(0) XDOT(1) XDOT(2) XDOT(3) XDOT(4) XDOT(5) XDOT(6) XDOT(7)

        if (s > 0) {
            HGRP(0) HGRP(1) HGRP(2) HGRP(3)
            HGRP(4) HGRP(5) HGRP(6) HGRP(7)
        }

        REDW(0) REDW(1) REDW(2) REDW(3) REDW(4) REDW(5) REDW(6) REDW(7)
        __syncthreads();

        // pointwise for (r2, m) and (r2, m+64); c-state in registers
        {
            const float* g0 = &s_g[r2 * 512];
            float ig = sigf(g0[m] + bi0);
            float fg = sigf(g0[128 + m] + bf0);
            float gt = tanhfast(g0[256 + m] + bg0);
            float og = sigf(g0[384 + m] + bo0);
            c0 = fmaf(fg, c0, ig * gt);
            s_h[r2 * HROW + hcol0] = og * tanhfast(c0);

            float ih = sigf(g0[64 + m] + bi1);
            float fh = sigf(g0[192 + m] + bf1);
            float gh = tanhfast(g0[320 + m] + bg1);
            float oh = sigf(g0[448 + m] + bo1);
            c1 = fmaf(fh, c1, ih * gh);
            s_h[r2 * HROW + hcol1] = oh * tanhfast(c1);
        }
        __syncthreads();
    }

    // epilogue: out[row0+r2][m] = b_out[m] + h[r2] . W_out[m]
    {
        float acc = b_out[m];
        const float4* wp = (const float4*)&W_out[m * 128];
        const float4* hq = (const float4*)&s_h[r2 * HROW];        // 33 f4/row
        #pragma unroll
        for (int kk = 0; kk < 32; ++kk) {
            float4 h4 = hq[kk < 16 ? kk : kk + 1];   // skip the 4-float gap
            float4 w4 = wp[kk];
            FMA4(acc, h4, w4)
        }
        out[(row0 + r2) * 64 + m] = acc;
    }
}

// ---------------------------------------------------------------------------
extern "C" void kernel_launch(void* const* d_in, const int* in_sizes, int n_in,
                              void* d_out, int out_size, void* d_ws, size_t ws_size,
                              hipStream_t stream) {
    (void)in_sizes; (void)n_in; (void)out_size; (void)ws_size;
    const float* seqs  = (const float*)d_in[0];
    const float* ets   = (const float*)d_in[1];
    const int*   masks = (const int*)d_in[2];
    const float* Wf  = (const float*)d_in[3];
    const float* bf  = (const float*)d_in[4];
    const float* Wk  = (const float*)d_in[5];
    const float* bk  = (const float*)d_in[6];
    const float* Wq  = (const float*)d_in[7];
    const float* bq  = (const float*)d_in[8];
    const float* Wv  = (const float*)d_in[9];
    const float* bv  = (const float*)d_in[10];
    const float* Wih = (const float*)d_in[11];
    const float* Whh = (const float*)d_in[12];
    const float* bih = (const float*)d_in[13];
    const float* bhh = (const float*)d_in[14];
    const float* Wo  = (const float*)d_in[15];
    const float* bo  = (const float*)d_in[16];

    float* ctx = (float*)d_ws;  // [BS,SEQ,64] fp32 = 26.2 MB

    hipLaunchKernelGGL(edge_attn_ctx, dim3(4096), dim3(64), 0, stream,
                       seqs, ets, masks, Wf, bf, Wk, bk, Wq, bq, Wv, bv, ctx);
    hipLaunchKernelGGL(lstm_out, dim3(256), dim3(512), 0, stream,
                       ctx, Wih, Whh, bih, bhh, Wo, bo, (float*)d_out);
}